// Round 1
// baseline (863.387 us; speedup 1.0000x reference)
//
#include <hip/hip_runtime.h>

// DGConv: K=2 diffusion steps of x <- (1-d)x + d * (D^-1/2 (A+I) D^-1/2) x, then x @ W + b.
// N=100000 nodes, E=1600000 edges, D=64 features. delta = 5.27/2 = 2.635.

#define TPB 256

__global__ void count_kernel(const int* __restrict__ dst, int* __restrict__ counts, int e) {
    int i = blockIdx.x * blockDim.x + threadIdx.x;
    if (i < e) atomicAdd(&counts[dst[i]], 1);
}

// Single-block exclusive scan over counts -> row_ptr (+ cursor copy), and dinv = rsqrt(deg+1).
__global__ void scan_build(const int* __restrict__ counts, int* __restrict__ row_ptr,
                           int* __restrict__ cursor, float* __restrict__ dinv,
                           int n, int e_total) {
    __shared__ int sums[1024];
    const int T = 1024;
    int t = threadIdx.x;
    int chunk = (n + T - 1) / T;
    int beg = t * chunk;
    int end = beg + chunk; if (end > n) end = n;
    int s = 0;
    for (int i = beg; i < end; ++i) s += counts[i];
    sums[t] = s;
    __syncthreads();
    // Hillis-Steele inclusive scan over the 1024 partials.
    for (int off = 1; off < T; off <<= 1) {
        int add = (t >= off) ? sums[t - off] : 0;
        __syncthreads();
        sums[t] += add;
        __syncthreads();
    }
    int running = sums[t] - s;  // exclusive prefix of this thread's chunk
    for (int i = beg; i < end; ++i) {
        row_ptr[i] = running;
        cursor[i]  = running;
        int c = counts[i];
        dinv[i] = rsqrtf((float)(c + 1));  // +1 for the self-loop; always > 0
        running += c;
    }
    if (t == 0) row_ptr[n] = e_total;
}

__global__ void fill_kernel(const int* __restrict__ src, const int* __restrict__ dst,
                            int* __restrict__ cursor, const float* __restrict__ dinv,
                            int* __restrict__ col, float* __restrict__ wgt, int e) {
    int i = blockIdx.x * blockDim.x + threadIdx.x;
    if (i >= e) return;
    int s = src[i], d = dst[i];
    int pos = atomicAdd(&cursor[d], 1);
    col[pos] = s;
    wgt[pos] = dinv[s] * dinv[d];
}

// One wave (64 lanes) per node; lane = feature index.
// x_new = (1-delta + delta*dinv^2)*x + delta * sum_e w_e * x[src_e]
__global__ void spmm_kernel(const float* __restrict__ xin, float* __restrict__ xout,
                            const int* __restrict__ row_ptr, const int* __restrict__ col,
                            const float* __restrict__ wgt, const float* __restrict__ dinv,
                            int n, float delta) {
    int node = blockIdx.x * (blockDim.x >> 6) + (threadIdx.x >> 6);
    int lane = threadIdx.x & 63;
    if (node >= n) return;
    float xi = xin[(size_t)node * 64 + lane];
    float dv = dinv[node];
    int beg = row_ptr[node], end = row_ptr[node + 1];
    float acc = 0.f;
    for (int j = beg; j < end; ++j) {
        int c = col[j];          // wave-uniform broadcast load
        float w = wgt[j];
        acc += w * xin[(size_t)c * 64 + lane];  // coalesced 256B row gather
    }
    float res = (1.f - delta) * xi + delta * (dv * dv * xi + acc);
    xout[(size_t)node * 64 + lane] = res;
}

// y[r][o] = b[o] + sum_k x[r][k] * W[k][o]; wave per row, W staged in LDS.
__global__ void gemm_kernel(const float* __restrict__ x, const float* __restrict__ W,
                            const float* __restrict__ b, float* __restrict__ y, int n) {
    __shared__ float Ws[64 * 64];
    __shared__ float bs[64];
    for (int i = threadIdx.x; i < 64 * 64; i += blockDim.x) Ws[i] = W[i];
    if (threadIdx.x < 64) bs[threadIdx.x] = b[threadIdx.x];
    __syncthreads();
    int row = blockIdx.x * (blockDim.x >> 6) + (threadIdx.x >> 6);
    int lane = threadIdx.x & 63;
    if (row >= n) return;
    float xv = x[(size_t)row * 64 + lane];
    float acc = bs[lane];
#pragma unroll
    for (int k = 0; k < 64; ++k) {
        acc += __shfl(xv, k) * Ws[k * 64 + lane];
    }
    y[(size_t)row * 64 + lane] = acc;
}

extern "C" void kernel_launch(void* const* d_in, const int* in_sizes, int n_in,
                              void* d_out, int out_size, void* d_ws, size_t ws_size,
                              hipStream_t stream) {
    const float* x  = (const float*)d_in[0];
    const int*   ei = (const int*)d_in[1];   // [2, E] row-major: src then dst
    const float* W  = (const float*)d_in[2];
    const float* b  = (const float*)d_in[3];
    float* out = (float*)d_out;

    const int N = in_sizes[0] / 64;
    const int E = in_sizes[1] / 2;
    const float delta = (float)(5.27 / 2.0);

    // Workspace layout (16B-aligned pieces first).
    char* p = (char*)d_ws;
    float* xbuf  = (float*)p;  p += (size_t)N * 64 * sizeof(float);
    int*   col   = (int*)p;    p += (size_t)E * sizeof(int);
    float* wgt   = (float*)p;  p += (size_t)E * sizeof(float);
    float* dinv  = (float*)p;  p += (size_t)N * sizeof(float);
    int*   counts= (int*)p;    p += (size_t)N * sizeof(int);
    int*   rowp  = (int*)p;    p += (size_t)(N + 1) * sizeof(int);
    int*   cursor= (int*)p;    p += (size_t)N * sizeof(int);

    hipMemsetAsync(counts, 0, (size_t)N * sizeof(int), stream);

    int grid_e = (E + TPB - 1) / TPB;
    int grid_n = (N + (TPB / 64) - 1) / (TPB / 64);

    count_kernel<<<grid_e, TPB, 0, stream>>>(ei + E, counts, E);
    scan_build<<<1, 1024, 0, stream>>>(counts, rowp, cursor, dinv, N, E);
    fill_kernel<<<grid_e, TPB, 0, stream>>>(ei, ei + E, cursor, dinv, col, wgt, E);

    // Step 1: x -> out (d_out used as ping buffer)
    spmm_kernel<<<grid_n, TPB, 0, stream>>>(x, out, rowp, col, wgt, dinv, N, delta);
    // Step 2: out -> xbuf
    spmm_kernel<<<grid_n, TPB, 0, stream>>>(out, xbuf, rowp, col, wgt, dinv, N, delta);
    // Linear: xbuf @ W + b -> out
    gemm_kernel<<<grid_n, TPB, 0, stream>>>(xbuf, W, b, out, N);
}

// Round 2
// 523.655 us; speedup vs baseline: 1.6488x; 1.6488x over previous
//
#include <hip/hip_runtime.h>

// DGConv: K=2 diffusion steps of x <- (1-d)x + d * (D^-1/2 (A+I) D^-1/2) x, then x @ W + b.
// N=100000 nodes, E=1600000 edges, D=64 features. delta = 5.27/2 = 2.635.

#define TPB 256
#define SCAN_T 256
#define SCAN_I 4
#define SCAN_CHUNK (SCAN_T * SCAN_I)   // 1024 elements per scan block

__global__ void count_kernel(const int* __restrict__ dst, int* __restrict__ counts, int e) {
    int i = blockIdx.x * blockDim.x + threadIdx.x;
    if (i < e) atomicAdd(&counts[dst[i]], 1);
}

// Pass 1: per-block sums of counts.
__global__ void scan_partials(const int* __restrict__ counts, int* __restrict__ bsums, int n) {
    __shared__ int red[SCAN_T];
    int t = threadIdx.x;
    int base = blockIdx.x * SCAN_CHUNK + t * SCAN_I;
    int s = 0;
#pragma unroll
    for (int k = 0; k < SCAN_I; ++k) { int i = base + k; if (i < n) s += counts[i]; }
    red[t] = s;
    __syncthreads();
    for (int off = SCAN_T / 2; off > 0; off >>= 1) {
        if (t < off) red[t] += red[t + off];
        __syncthreads();
    }
    if (t == 0) bsums[blockIdx.x] = red[0];
}

// Pass 2: exclusive scan of the (<=512) block sums, single block. Also sets row_ptr[n]=e.
__global__ void scan_bsums(int* __restrict__ bsums, int nb, int* __restrict__ row_ptr,
                           int n, int e) {
    __shared__ int s[512];
    int t = threadIdx.x;
    int v = (t < nb) ? bsums[t] : 0;
    s[t] = v;
    __syncthreads();
    for (int off = 1; off < 512; off <<= 1) {
        int a = (t >= off) ? s[t - off] : 0;
        __syncthreads();
        s[t] += a;
        __syncthreads();
    }
    if (t < nb) bsums[t] = s[t] - v;   // exclusive prefix
    if (t == 0) row_ptr[n] = e;
}

// Pass 3: per-block rescan + emit row_ptr/cursor/dinv.
__global__ void scan_emit(const int* __restrict__ counts, const int* __restrict__ boffs,
                          int* __restrict__ row_ptr, int* __restrict__ cursor,
                          float* __restrict__ dinv, int n) {
    __shared__ int red[SCAN_T];
    int t = threadIdx.x;
    int base = blockIdx.x * SCAN_CHUNK + t * SCAN_I;
    int c[SCAN_I];
    int s = 0;
#pragma unroll
    for (int k = 0; k < SCAN_I; ++k) { int i = base + k; c[k] = (i < n) ? counts[i] : 0; s += c[k]; }
    red[t] = s;
    __syncthreads();
    for (int off = 1; off < SCAN_T; off <<= 1) {      // inclusive Hillis-Steele
        int a = (t >= off) ? red[t - off] : 0;
        __syncthreads();
        red[t] += a;
        __syncthreads();
    }
    int run = boffs[blockIdx.x] + red[t] - s;          // exclusive prefix for this thread
#pragma unroll
    for (int k = 0; k < SCAN_I; ++k) {
        int i = base + k;
        if (i < n) {
            row_ptr[i] = run;
            cursor[i]  = run;
            dinv[i] = rsqrtf((float)(c[k] + 1));       // +1 self-loop; always > 0
            run += c[k];
        }
    }
}

__global__ void fill_kernel(const int* __restrict__ src, const int* __restrict__ dst,
                            int* __restrict__ cursor, const float* __restrict__ dinv,
                            int* __restrict__ col, float* __restrict__ wgt, int e) {
    int i = blockIdx.x * blockDim.x + threadIdx.x;
    if (i >= e) return;
    int s = src[i], d = dst[i];
    int pos = atomicAdd(&cursor[d], 1);
    col[pos] = s;
    wgt[pos] = dinv[s] * dinv[d];
}

// One wave per node; lane = feature. x_new = (1-d + d*dinv^2)*x + d * sum_e w_e x[src_e]
__global__ void spmm_kernel(const float* __restrict__ xin, float* __restrict__ xout,
                            const int* __restrict__ row_ptr, const int* __restrict__ col,
                            const float* __restrict__ wgt, const float* __restrict__ dinv,
                            int n, float delta) {
    int node = blockIdx.x * (blockDim.x >> 6) + (threadIdx.x >> 6);
    int lane = threadIdx.x & 63;
    if (node >= n) return;
    float xi = xin[(size_t)node * 64 + lane];
    float dv = dinv[node];
    int beg = row_ptr[node], end = row_ptr[node + 1];
    float acc = 0.f;
    for (int j = beg; j < end; ++j) {
        acc += wgt[j] * xin[(size_t)col[j] * 64 + lane];  // coalesced 256B row gather
    }
    xout[(size_t)node * 64 + lane] = (1.f - delta) * xi + delta * (dv * dv * xi + acc);
}

// Step-2 SpMM fused with y = x2 @ W + b (shfl-broadcast row, W staged in LDS).
__global__ void spmm_gemm_kernel(const float* __restrict__ xin, float* __restrict__ y,
                                 const int* __restrict__ row_ptr, const int* __restrict__ col,
                                 const float* __restrict__ wgt, const float* __restrict__ dinv,
                                 const float* __restrict__ W, const float* __restrict__ b,
                                 int n, float delta) {
    __shared__ float Ws[64 * 64];
    __shared__ float bs[64];
    for (int i = threadIdx.x; i < 64 * 64; i += blockDim.x) Ws[i] = W[i];
    if (threadIdx.x < 64) bs[threadIdx.x] = b[threadIdx.x];
    __syncthreads();
    int node = blockIdx.x * (blockDim.x >> 6) + (threadIdx.x >> 6);
    int lane = threadIdx.x & 63;
    if (node >= n) return;
    float xi = xin[(size_t)node * 64 + lane];
    float dv = dinv[node];
    int beg = row_ptr[node], end = row_ptr[node + 1];
    float acc = 0.f;
    for (int j = beg; j < end; ++j) {
        acc += wgt[j] * xin[(size_t)col[j] * 64 + lane];
    }
    float res = (1.f - delta) * xi + delta * (dv * dv * xi + acc);
    float o = bs[lane];
#pragma unroll
    for (int k = 0; k < 64; ++k) {
        o += __shfl(res, k) * Ws[k * 64 + lane];   // stride-1 across lanes: conflict-free
    }
    y[(size_t)node * 64 + lane] = o;
}

extern "C" void kernel_launch(void* const* d_in, const int* in_sizes, int n_in,
                              void* d_out, int out_size, void* d_ws, size_t ws_size,
                              hipStream_t stream) {
    const float* x  = (const float*)d_in[0];
    const int*   ei = (const int*)d_in[1];   // [2, E] row-major: src then dst
    const float* W  = (const float*)d_in[2];
    const float* b  = (const float*)d_in[3];
    float* out = (float*)d_out;

    const int N = in_sizes[0] / 64;
    const int E = in_sizes[1] / 2;
    const float delta = (float)(5.27 / 2.0);

    // Workspace layout.
    char* p = (char*)d_ws;
    float* xbuf  = (float*)p;  p += (size_t)N * 64 * sizeof(float);
    int*   col   = (int*)p;    p += (size_t)E * sizeof(int);
    float* wgt   = (float*)p;  p += (size_t)E * sizeof(float);
    float* dinv  = (float*)p;  p += (size_t)N * sizeof(float);
    int*   counts= (int*)p;    p += (size_t)N * sizeof(int);
    int*   rowp  = (int*)p;    p += (size_t)(N + 1) * sizeof(int);
    int*   cursor= (int*)p;    p += (size_t)N * sizeof(int);
    int*   bsums = (int*)p;    p += 512 * sizeof(int);

    hipMemsetAsync(counts, 0, (size_t)N * sizeof(int), stream);

    int grid_e = (E + TPB - 1) / TPB;
    int grid_n = (N + (TPB / 64) - 1) / (TPB / 64);
    int nb_scan = (N + SCAN_CHUNK - 1) / SCAN_CHUNK;   // 98 for N=100000

    count_kernel<<<grid_e, TPB, 0, stream>>>(ei + E, counts, E);
    scan_partials<<<nb_scan, SCAN_T, 0, stream>>>(counts, bsums, N);
    scan_bsums<<<1, 512, 0, stream>>>(bsums, nb_scan, rowp, N, E);
    scan_emit<<<nb_scan, SCAN_T, 0, stream>>>(counts, bsums, rowp, cursor, dinv, N);
    fill_kernel<<<grid_e, TPB, 0, stream>>>(ei, ei + E, cursor, dinv, col, wgt, E);

    // Step 1: x -> xbuf
    spmm_kernel<<<grid_n, TPB, 0, stream>>>(x, xbuf, rowp, col, wgt, dinv, N, delta);
    // Step 2 + linear, fused: xbuf -> out
    spmm_gemm_kernel<<<grid_n, TPB, 0, stream>>>(xbuf, out, rowp, col, wgt, dinv, W, b, N, delta);
}

// Round 3
// 372.509 us; speedup vs baseline: 2.3178x; 1.4057x over previous
//
#include <hip/hip_runtime.h>

// DGConv: K=2 diffusion steps of x <- (1-d)x + d * (D^-1/2 (A+I) D^-1/2) x, then x @ W + b.
// N=100000 nodes, E=1600000 edges, D=64 features. delta = 5.27/2 = 2.635.

#define TPB 256
#define SCAN_T 256
#define SCAN_I 4
#define SCAN_CHUNK (SCAN_T * SCAN_I)   // 1024 elements per scan block

__global__ void count_kernel(const int* __restrict__ dst, int* __restrict__ counts, int e) {
    int i = blockIdx.x * blockDim.x + threadIdx.x;
    if (i < e) atomicAdd(&counts[dst[i]], 1);
}

// Pass 1: per-block sums of counts.
__global__ void scan_partials(const int* __restrict__ counts, int* __restrict__ bsums, int n) {
    __shared__ int red[SCAN_T];
    int t = threadIdx.x;
    int base = blockIdx.x * SCAN_CHUNK + t * SCAN_I;
    int s = 0;
#pragma unroll
    for (int k = 0; k < SCAN_I; ++k) { int i = base + k; if (i < n) s += counts[i]; }
    red[t] = s;
    __syncthreads();
    for (int off = SCAN_T / 2; off > 0; off >>= 1) {
        if (t < off) red[t] += red[t + off];
        __syncthreads();
    }
    if (t == 0) bsums[blockIdx.x] = red[0];
}

// Pass 2: exclusive scan of the (<=512) block sums, single block. Also sets row_ptr[n]=e.
__global__ void scan_bsums(int* __restrict__ bsums, int nb, int* __restrict__ row_ptr,
                           int n, int e) {
    __shared__ int s[512];
    int t = threadIdx.x;
    int v = (t < nb) ? bsums[t] : 0;
    s[t] = v;
    __syncthreads();
    for (int off = 1; off < 512; off <<= 1) {
        int a = (t >= off) ? s[t - off] : 0;
        __syncthreads();
        s[t] += a;
        __syncthreads();
    }
    if (t < nb) bsums[t] = s[t] - v;   // exclusive prefix
    if (t == 0) row_ptr[n] = e;
}

// Pass 3: per-block rescan + emit row_ptr/cursor/dinv.
__global__ void scan_emit(const int* __restrict__ counts, const int* __restrict__ boffs,
                          int* __restrict__ row_ptr, int* __restrict__ cursor,
                          float* __restrict__ dinv, int n) {
    __shared__ int red[SCAN_T];
    int t = threadIdx.x;
    int base = blockIdx.x * SCAN_CHUNK + t * SCAN_I;
    int c[SCAN_I];
    int s = 0;
#pragma unroll
    for (int k = 0; k < SCAN_I; ++k) { int i = base + k; c[k] = (i < n) ? counts[i] : 0; s += c[k]; }
    red[t] = s;
    __syncthreads();
    for (int off = 1; off < SCAN_T; off <<= 1) {      // inclusive Hillis-Steele
        int a = (t >= off) ? red[t - off] : 0;
        __syncthreads();
        red[t] += a;
        __syncthreads();
    }
    int run = boffs[blockIdx.x] + red[t] - s;          // exclusive prefix for this thread
#pragma unroll
    for (int k = 0; k < SCAN_I; ++k) {
        int i = base + k;
        if (i < n) {
            row_ptr[i] = run;
            cursor[i]  = run;
            dinv[i] = rsqrtf((float)(c[k] + 1));       // +1 self-loop; always > 0
            run += c[k];
        }
    }
}

// Emit packed (col, wgt) pairs: one 8B store per edge instead of two 4B scattered stores.
__global__ void fill_kernel(const int* __restrict__ src, const int* __restrict__ dst,
                            int* __restrict__ cursor, const float* __restrict__ dinv,
                            int2* __restrict__ cw, int e) {
    int i = blockIdx.x * blockDim.x + threadIdx.x;
    if (i >= e) return;
    int s = src[i], d = dst[i];
    int pos = atomicAdd(&cursor[d], 1);
    int2 p;
    p.x = s;
    p.y = __float_as_int(dinv[s] * dinv[d]);
    cw[pos] = p;
}

// Batch-8 pipelined gather: 8 independent (col,wgt) loads -> 8 independent x-row gathers
// -> 8 FMAs. Tail clamped with zero weight (wave-uniform predicate, no divergence).
__device__ __forceinline__ float spmm_row(const float* __restrict__ xin,
                                          const int2* __restrict__ cw,
                                          int beg, int end, int lane) {
    float acc = 0.f;
    for (int j = beg; j < end; j += 8) {
        int c[8]; float w[8];
#pragma unroll
        for (int k = 0; k < 8; ++k) {
            int jj = j + k;
            bool v = jj < end;
            int2 p = cw[v ? jj : beg];
            c[k] = p.x;
            w[k] = v ? __int_as_float(p.y) : 0.f;
        }
        float xv[8];
#pragma unroll
        for (int k = 0; k < 8; ++k) xv[k] = xin[(size_t)c[k] * 64 + lane];
#pragma unroll
        for (int k = 0; k < 8; ++k) acc = fmaf(w[k], xv[k], acc);
    }
    return acc;
}

// One wave per node; lane = feature. x_new = (1-d + d*dinv^2)*x + d * sum_e w_e x[src_e]
__global__ void spmm_kernel(const float* __restrict__ xin, float* __restrict__ xout,
                            const int* __restrict__ row_ptr, const int2* __restrict__ cw,
                            const float* __restrict__ dinv, int n, float delta) {
    int node = blockIdx.x * (blockDim.x >> 6) + (threadIdx.x >> 6);
    int lane = threadIdx.x & 63;
    if (node >= n) return;
    float xi = xin[(size_t)node * 64 + lane];
    float dv = dinv[node];
    int beg = row_ptr[node], end = row_ptr[node + 1];
    float acc = spmm_row(xin, cw, beg, end, lane);
    xout[(size_t)node * 64 + lane] = (1.f - delta) * xi + delta * (dv * dv * xi + acc);
}

// Step-2 SpMM fused with y = x2 @ W + b (shfl-broadcast row, W staged in LDS).
__global__ void spmm_gemm_kernel(const float* __restrict__ xin, float* __restrict__ y,
                                 const int* __restrict__ row_ptr, const int2* __restrict__ cw,
                                 const float* __restrict__ dinv,
                                 const float* __restrict__ W, const float* __restrict__ b,
                                 int n, float delta) {
    __shared__ float Ws[64 * 64];
    __shared__ float bs[64];
    for (int i = threadIdx.x; i < 64 * 64; i += blockDim.x) Ws[i] = W[i];
    if (threadIdx.x < 64) bs[threadIdx.x] = b[threadIdx.x];
    __syncthreads();
    int node = blockIdx.x * (blockDim.x >> 6) + (threadIdx.x >> 6);
    int lane = threadIdx.x & 63;
    if (node >= n) return;
    float xi = xin[(size_t)node * 64 + lane];
    float dv = dinv[node];
    int beg = row_ptr[node], end = row_ptr[node + 1];
    float acc = spmm_row(xin, cw, beg, end, lane);
    float res = (1.f - delta) * xi + delta * (dv * dv * xi + acc);
    float o = bs[lane];
#pragma unroll
    for (int k = 0; k < 64; ++k) {
        o += __shfl(res, k) * Ws[k * 64 + lane];   // stride-1 across lanes: conflict-free
    }
    y[(size_t)node * 64 + lane] = o;
}

extern "C" void kernel_launch(void* const* d_in, const int* in_sizes, int n_in,
                              void* d_out, int out_size, void* d_ws, size_t ws_size,
                              hipStream_t stream) {
    const float* x  = (const float*)d_in[0];
    const int*   ei = (const int*)d_in[1];   // [2, E] row-major: src then dst
    const float* W  = (const float*)d_in[2];
    const float* b  = (const float*)d_in[3];
    float* out = (float*)d_out;

    const int N = in_sizes[0] / 64;
    const int E = in_sizes[1] / 2;
    const float delta = (float)(5.27 / 2.0);

    // Workspace layout.
    char* p = (char*)d_ws;
    float* xbuf  = (float*)p;  p += (size_t)N * 64 * sizeof(float);
    int2*  cw    = (int2*)p;   p += (size_t)E * sizeof(int2);
    float* dinv  = (float*)p;  p += (size_t)N * sizeof(float);
    int*   counts= (int*)p;    p += (size_t)N * sizeof(int);
    int*   rowp  = (int*)p;    p += (size_t)(N + 1) * sizeof(int);
    int*   cursor= (int*)p;    p += (size_t)N * sizeof(int);
    int*   bsums = (int*)p;    p += 512 * sizeof(int);

    hipMemsetAsync(counts, 0, (size_t)N * sizeof(int), stream);

    int grid_e = (E + TPB - 1) / TPB;
    int grid_n = (N + (TPB / 64) - 1) / (TPB / 64);
    int nb_scan = (N + SCAN_CHUNK - 1) / SCAN_CHUNK;   // 98 for N=100000

    count_kernel<<<grid_e, TPB, 0, stream>>>(ei + E, counts, E);
    scan_partials<<<nb_scan, SCAN_T, 0, stream>>>(counts, bsums, N);
    scan_bsums<<<1, 512, 0, stream>>>(bsums, nb_scan, rowp, N, E);
    scan_emit<<<nb_scan, SCAN_T, 0, stream>>>(counts, bsums, rowp, cursor, dinv, N);
    fill_kernel<<<grid_e, TPB, 0, stream>>>(ei, ei + E, cursor, dinv, cw, E);

    // Step 1: x -> xbuf
    spmm_kernel<<<grid_n, TPB, 0, stream>>>(x, xbuf, rowp, cw, dinv, N, delta);
    // Step 2 + linear, fused: xbuf -> out
    spmm_gemm_kernel<<<grid_n, TPB, 0, stream>>>(xbuf, out, rowp, cw, dinv, W, b, N, delta);
}